// Round 14
// baseline (197.505 us; speedup 1.0000x reference)
//
#include <hip/hip_runtime.h>
#include <math.h>

#define KTOT 69
#define NRADC 24
#define NFEAT 216
#define NELEMC 94
#define EMBC 16
#define H1C 256
#define H2C 128
#define CE 16          // edges per chunk in k_atom
#define EPR 20         // padded edge stride for s_radT rows
#define KGN 18         // padded k-groups (72 padded k / 4)
#define GSTR 84        // s_gijT kg-stride
#define GISTR 76       // s_gi rad-stride
#define TA 2           // atoms per species-pure tile (R14: 4->2, TLP gradient)
#define NPT 1072       // padded tiles (1072*2=2144 >= 2048 + 94)

// ---- static lxlylz enumeration (z=1..4 concatenated; real k = 0..68) ----
__device__ __constant__ int c_lx[KTOT] = {
  0,0,0,1,
  0,0,0,1,0,0,0,1,1,2,
  0,0,0,1,0,0,0,1,1,2,0,0,0,0,1,1,1,2,2,3,
  0,0,0,1,0,0,0,1,1,2,0,0,0,0,1,1,1,2,2,3,0,0,0,0,0,1,1,1,1,2,2,2,3,3,4};
__device__ __constant__ int c_ly[KTOT] = {
  0,0,1,0,
  0,0,1,0,0,1,2,0,1,0,
  0,0,1,0,0,1,2,0,1,0,0,1,2,3,0,1,2,0,1,0,
  0,0,1,0,0,1,2,0,1,0,0,1,2,3,0,1,2,0,1,0,0,1,2,3,4,0,1,2,3,0,1,2,0,1,0};
__device__ __constant__ int c_lz[KTOT] = {
  0,1,0,0,
  0,1,0,0,2,1,0,1,0,0,
  0,1,0,0,2,1,0,1,0,0,3,2,1,0,2,1,0,1,0,0,
  0,1,0,0,2,1,0,1,0,0,3,2,1,0,2,1,0,1,0,0,4,3,2,1,0,3,2,1,0,2,1,0,1,0,0};
__device__ __constant__ float c_fn[KTOT] = {
  1,1,1,1,
  1,2,2,2,1,2,1,2,2,1,
  1,3,3,3,3,6,3,6,6,3,1,3,3,1,3,6,3,3,3,1,
  1,4,4,4,6,12,6,12,12,6,4,12,12,4,12,24,12,12,12,4,
  1,4,6,4,1,4,12,12,4,6,12,6,4,4,1};
__device__ __constant__ float c_lam[KTOT] = {
  1,-1,-1,-1,
  1,-1,-1,-1,1,1,1,1,1,1,
  1,-1,-1,-1,1,1,1,1,1,1,-1,-1,-1,-1,-1,-1,-1,-1,-1,-1,
  1,-1,-1,-1,1,1,1,1,1,1,-1,-1,-1,-1,-1,-1,-1,-1,-1,-1,
  1,1,1,1,1,1,1,1,1,1,1,1,1,1,1};
__device__ __constant__ int c_k0[4] = {0,4,14,34};
__device__ __constant__ int c_kn[4] = {4,10,20,35};
__device__ __constant__ float c_zn[4] = {1.0f, 0.5f, 0.25f, 0.125f};
__device__ __constant__ int c_zidg[KGN] = {0, 1,1,1, 2,2,2,2,2, 3,3,3,3,3,3,3,3,3};

__device__ __forceinline__ float silu(float x) { return x / (1.0f + expf(-x)); }
__device__ __forceinline__ float4 silu4(float4 v) {
  v.x = silu(v.x); v.y = silu(v.y); v.z = silu(v.z); v.w = silu(v.w); return v;
}
__device__ __forceinline__ void fma4(float4& a, float s, const float4 w) {
  a.x += s * w.x; a.y += s * w.y; a.z += s * w.z; a.w += s * w.w;
}
__device__ __forceinline__ void fma44(float4& a, const float4 x, const float4 y) {
  a.x += x.x * y.x; a.y += x.y * y.y; a.z += x.z * y.z; a.w += x.w * y.w;
}
__device__ __forceinline__ float hsum4(const float4 v) { return (v.x + v.y) + (v.z + v.w); }
__device__ __forceinline__ float powsel(int l, float p, float p2, float p3, float p4) {
  float v = 1.0f;
  v = l >= 1 ? p : v;
  v = l >= 2 ? p2 : v;
  v = l >= 3 ? p3 : v;
  v = l >= 4 ? p4 : v;
  return v;
}

// ====== k_front: edge radial MLP + bounds + padded sort + B, ONE launch =====
template <int NQ>
__device__ __forceinline__ void edge_l2(
    const float* __restrict__ s_h, const float* __restrict__ Wr2,
    const float* __restrict__ br2, float4* __restrict__ radial4,
    int e, int og, int eg, int E) {
  float4 acc[NQ];
  const float4* b2 = (const float4*)(br2 + og * 32);
  #pragma unroll
  for (int q = 0; q < NQ; ++q) acc[q] = b2[q];
  #pragma unroll 8
  for (int j = 0; j < 64; ++j) {
    float hv = s_h[e * 65 + j];
    const float4* w = (const float4*)(Wr2 + j * 120 + og * 32);
    #pragma unroll
    for (int q = 0; q < NQ; ++q) fma4(acc[q], hv, w[q]);
  }
  if (eg < E) {
    #pragma unroll
    for (int q = 0; q < NQ; ++q)
      radial4[(size_t)eg * 30 + og * 8 + q] = silu4(acc[q]);
  }
}

__global__ __launch_bounds__(256) void k_front(
    const float* __restrict__ rij,
    const float* __restrict__ Wr1, const float* __restrict__ br1,
    const float* __restrict__ Wr2, const float* __restrict__ br2,
    const int* __restrict__ fai, const int* __restrict__ spc,
    const float* __restrict__ Ws1, const float* __restrict__ bs1,
    const float* __restrict__ Ws2, const float* __restrict__ bs2,
    const float* __restrict__ Wa1,
    float4* __restrict__ radial4, int* __restrict__ bounds,
    int* __restrict__ porder, float* __restrict__ B,
    float* __restrict__ out0,
    int E, int nat, int nbE, int nbB) {
  __shared__ __align__(16) float s_mem[64 * 25 + 64 * 65];  // 23 KB union
  const int blk = blockIdx.x;
  const int tid = threadIdx.x;

  if (blk < nbE) {
    // ------------------------- edge branch -------------------------
    float* s_bas = s_mem;              // [64][25]
    float* s_h = s_mem + 64 * 25;      // [64][65]
    const int e = tid & 63;
    const int og = __builtin_amdgcn_readfirstlane(tid >> 6);
    const int eg = blk * 64 + e;
    {
      float x = 0.0f, y = 0.0f, z = 0.0f;
      const bool ev = eg < E;
      if (ev) { x = rij[3 * eg]; y = rij[3 * eg + 1]; z = rij[3 * eg + 2]; }
      float r = sqrtf(x * x + y * y + z * z);
      float fcv = ev ? 0.5f * (cosf(3.14159265358979323846f * fminf(r, 6.0f) *
                                    (1.0f / 6.0f)) + 1.0f)
                     : 0.0f;
      #pragma unroll
      for (int t = 0; t < 6; ++t) {
        int m = og * 6 + t;
        float d = r - (6.0f / 23.0f) * (float)m;
        s_bas[e * 25 + m] = expf(-8.0f * d * d) * fcv;
      }
    }
    __syncthreads();
    {
      const float4* b1 = (const float4*)(br1 + og * 16);
      float4 acc[4] = {b1[0], b1[1], b1[2], b1[3]};
      #pragma unroll 8
      for (int m = 0; m < NRADC; ++m) {
        float b = s_bas[e * 25 + m];
        const float4* w = (const float4*)(Wr1 + m * 64 + og * 16);
        #pragma unroll
        for (int q = 0; q < 4; ++q) fma4(acc[q], b, w[q]);
      }
      #pragma unroll
      for (int q = 0; q < 4; ++q) {
        float4 v = silu4(acc[q]);
        float* dst = &s_h[e * 65 + og * 16 + 4 * q];
        dst[0] = v.x; dst[1] = v.y; dst[2] = v.z; dst[3] = v.w;
      }
    }
    __syncthreads();
    if (og < 3) edge_l2<8>(s_h, Wr2, br2, radial4, e, og, eg, E);
    else        edge_l2<6>(s_h, Wr2, br2, radial4, e, og, eg, E);
  } else if (blk < nbE + nbB) {
    // ------------------------- bounds branch -----------------------
    int e = (blk - nbE) * 256 + tid;
    if (e < E) {
      int f = fai[e];
      int fp = (e == 0) ? -1 : fai[e - 1];
      for (int a = fp + 1; a <= f; ++a) bounds[a] = e;
      if (e == E - 1)
        for (int a = f + 1; a <= nat; ++a) bounds[a] = E;
    }
  } else if (blk == nbE + nbB) {
    // ------------------------- padded sort + out zero --------------
    int* s_cnt = (int*)s_mem;
    int* s_off = s_cnt + NELEMC;
    if (tid == 0) out0[0] = 0.0f;   // d_out accumulator init (pre-k_mlp)
    for (int i = tid; i < NELEMC; i += 256) s_cnt[i] = 0;
    __syncthreads();
    for (int a = tid; a < nat; a += 256) atomicAdd(&s_cnt[spc[a]], 1);
    __syncthreads();
    if (tid == 0) {
      int run = 0;
      for (int s = 0; s < NELEMC; ++s) {
        s_off[s] = run;
        run += ((s_cnt[s] + TA - 1) / TA) * TA;
      }
    }
    for (int i = tid; i < NPT * TA; i += 256) porder[i] = -1;
    __syncthreads();
    for (int a = tid; a < nat; a += 256) {
      int pos = atomicAdd(&s_off[spc[a]], 1);
      porder[pos] = a;
    }
  } else {
    // ------------------------- B branch ----------------------------
    float* s_hh = s_mem;               // [24][32]
    float* s_emb = s_mem + 24 * 32;    // [24][16]
    const int bi = blk - (nbE + nbB + 1);
    const int i = bi >> 2;
    const int sc0 = (bi & 3) * 24;
    const int scn = min(NELEMC, sc0 + 24) - sc0;
    const int o = tid;
    for (int idx = tid; idx < scn * 32; idx += 256) {
      int s = idx >> 5, c = idx & 31;
      s_hh[idx] = silu(Ws1[(sc0 + s) * 32 + c] + bs1[c]);
    }
    __syncthreads();
    for (int idx = tid; idx < scn * EMBC; idx += 256) {
      int s = idx >> 4, j = idx & 15;
      float acc = bs2[j];
      #pragma unroll
      for (int c = 0; c < 32; ++c) acc += s_hh[s * 32 + c] * Ws2[c * EMBC + j];
      s_emb[idx] = acc;
    }
    __syncthreads();
    float w[EMBC];
    #pragma unroll
    for (int j = 0; j < EMBC; ++j) w[j] = Wa1[(size_t)(i * EMBC + j) * H1C + o];
    for (int s = 0; s < scn; ++s) {
      float acc = 0.0f;
      #pragma unroll
      for (int j = 0; j < EMBC; ++j) acc += s_emb[s * EMBC + j] * w[j];
      B[((size_t)(sc0 + s) * NFEAT + i) * H1C + o] = acc;
    }
  }
}

// ========= k_atom v4: register-tiled + software-pipelined prefetch ==========
__global__ __launch_bounds__(256) void k_atom(
    const float* __restrict__ rij,
    const float4* __restrict__ radial4,
    const int* __restrict__ bounds,
    float* __restrict__ feat, int E) {
  const int a = blockIdx.x;
  const int tid = threadIdx.x;
  __shared__ __align__(16) float s_radT[120 * EPR];
  __shared__ __align__(16) float s_gijT[KGN * GSTR];
  __shared__ __align__(16) float s_gi[NRADC * GISTR];
  __shared__ float s_feat[NFEAT];

  const int start = bounds[a];
  const int end = bounds[a + 1];

  const int e = tid & 15;
  const int sub = tid >> 4;

  const bool is_tile = tid < 216;
  const int eh = (tid < 216) ? (tid / 108) : 0;
  const int tile = (tid < 216) ? (tid % 108) : 0;
  const int rg = tile % 6;
  const int kg = tile / 6;
  const int comp0 = rg * 20 + 1 + c_zidg[kg];
  const bool is_2b = (tid >= 216 && tid < 240);
  const int rad2b = tid - 216;

  const int kstart = sub < 5 ? sub * 5 : 25 + (sub - 5) * 4;
  const int kcnt = sub < 5 ? 5 : 4;
  int t_pk[5], t_addr[5]; float t_fn[5];
  #pragma unroll
  for (int t = 0; t < 5; ++t) {
    int k = (t < kcnt) ? kstart + t : 0;
    t_pk[t] = c_lx[k] | (c_ly[k] << 8) | (c_lz[k] << 16);
    t_fn[t] = c_fn[k];
    int prow = k + (k < 14 ? 0 : 2);
    t_addr[t] = (prow >> 2) * GSTR + (prow & 3) * EPR + e;
  }

  const int pe0 = tid / 30, pc0 = tid - pe0 * 30;
  const int pe1 = (tid + 256) / 30, pc1 = (tid + 256) - pe1 * 30;

  if (tid < 60) {
    int rr = tid / EPR, ec = tid % EPR;
    int fkg = rr < 2 ? 3 : 17;
    int fj = rr < 2 ? 2 + rr : 3;
    s_gijT[fkg * GSTR + fj * EPR + ec] = 0.0f;
  }

  float4 acc[4][4];
  #pragma unroll
  for (int i = 0; i < 4; ++i)
    #pragma unroll
    for (int j = 0; j < 4; ++j) acc[i][j] = make_float4(0, 0, 0, 0);
  float4 acc2b = make_float4(0, 0, 0, 0);

  float4 pfA, pfB;
  float rx, ry, rz;
  auto prefetch = [&](int c0) {
    int lim = (end - c0) * 30;
    pfA = make_float4(0, 0, 0, 0);
    pfB = make_float4(0, 0, 0, 0);
    if (tid < lim) pfA = radial4[(size_t)c0 * 30 + tid];
    if (tid < 224 && tid + 256 < lim) pfB = radial4[(size_t)c0 * 30 + 256 + tid];
    int eg = c0 + e;
    rx = 0.0f; ry = 0.0f; rz = 0.0f;
    if (eg < end) { rx = rij[3 * eg]; ry = rij[3 * eg + 1]; rz = rij[3 * eg + 2]; }
  };
  prefetch(start);

  for (int c0 = start; c0 < end; c0 += CE) {
    __syncthreads();
    {
      int c = pc0 * 4;
      s_radT[(c + 0) * EPR + pe0] = pfA.x;
      s_radT[(c + 1) * EPR + pe0] = pfA.y;
      s_radT[(c + 2) * EPR + pe0] = pfA.z;
      s_radT[(c + 3) * EPR + pe0] = pfA.w;
      if (tid < 224) {
        int c2 = pc1 * 4;
        s_radT[(c2 + 0) * EPR + pe1] = pfB.x;
        s_radT[(c2 + 1) * EPR + pe1] = pfB.y;
        s_radT[(c2 + 2) * EPR + pe1] = pfB.z;
        s_radT[(c2 + 3) * EPR + pe1] = pfB.w;
      }
    }
    {
      const bool ev = (c0 + e) < end;
      float r = sqrtf(rx * rx + ry * ry + rz * rz);
      float inv = 1.0f / r;
      float px = rx * inv + 1e-12f, py = ry * inv + 1e-12f, pz = rz * inv + 1e-12f;
      float p2x = px * px, p3x = p2x * px, p4x = p2x * p2x;
      float p2y = py * py, p3y = p2y * py, p4y = p2y * p2y;
      float p2z = pz * pz, p3z = p2z * pz, p4z = p2z * p2z;
      #pragma unroll
      for (int t = 0; t < 5; ++t) {
        if (t < kcnt) {
          int pk = t_pk[t];
          float g = powsel(pk & 0xff, px, p2x, p3x, p4x) *
                    powsel((pk >> 8) & 0xff, py, p2y, p3y, p4y) *
                    powsel(pk >> 16, pz, p2z, p3z, p4z) * t_fn[t];
          s_gijT[t_addr[t]] = ev ? g : 0.0f;
        }
      }
    }
    __syncthreads();
    prefetch(c0 + CE);
    if (is_tile) {
      #pragma unroll
      for (int s = 0; s < 2; ++s) {
        int e0 = eh * 8 + s * 4;
        float4 gg[4];
        #pragma unroll
        for (int j = 0; j < 4; ++j)
          gg[j] = *(const float4*)&s_gijT[kg * GSTR + j * EPR + e0];
        #pragma unroll
        for (int i = 0; i < 4; ++i) {
          float4 rr = *(const float4*)&s_radT[(comp0 + 5 * i) * EPR + e0];
          #pragma unroll
          for (int j = 0; j < 4; ++j) fma44(acc[i][j], rr, gg[j]);
        }
      }
    }
    if (is_2b) {
      #pragma unroll
      for (int e0 = 0; e0 < 16; e0 += 4) {
        float4 v = *(const float4*)&s_radT[(rad2b * 5) * EPR + e0];
        acc2b.x += v.x; acc2b.y += v.y; acc2b.z += v.z; acc2b.w += v.w;
      }
    }
  }

  float4 hs[4];
  #pragma unroll
  for (int i = 0; i < 4; ++i)
    hs[i] = make_float4(hsum4(acc[i][0]), hsum4(acc[i][1]),
                        hsum4(acc[i][2]), hsum4(acc[i][3]));
  __syncthreads();
  if (is_tile && eh == 0) {
    #pragma unroll
    for (int i = 0; i < 4; ++i)
      *(float4*)&s_gi[(rg * 4 + i) * GISTR + kg * 4] = hs[i];
  }
  if (is_2b) s_feat[rad2b] = hsum4(acc2b);
  __syncthreads();
  if (is_tile && eh == 1) {
    #pragma unroll
    for (int i = 0; i < 4; ++i) {
      float4 v = *(const float4*)&s_gi[(rg * 4 + i) * GISTR + kg * 4];
      v.x += hs[i].x; v.y += hs[i].y; v.z += hs[i].z; v.w += hs[i].w;
      *(float4*)&s_gi[(rg * 4 + i) * GISTR + kg * 4] = v;
    }
  }
  __syncthreads();

  if (tid < 192) {
    int zb = tid / NRADC;
    int rad = tid - zb * NRADC;
    int z = zb >> 1;
    bool neg = zb & 1;
    int k0 = c_k0[z], kn = c_kn[z];
    float s = 0.0f;
    for (int k = k0; k < k0 + kn; ++k) {
      int prow = k + (k < 14 ? 0 : 2);
      float g = s_gi[rad * GISTR + prow];
      float g2 = g * g;
      s += neg ? g2 * c_lam[k] : g2;
    }
    s_feat[NRADC + zb * NRADC + rad] = s * c_zn[z];
  }
  __syncthreads();
  if (tid < NFEAT) feat[(size_t)a * NFEAT + tid] = s_feat[tid];
}

// ====== k_mlp: fused layer1+layer2 per species-pure 2-atom tile + atomic sum =
__global__ __launch_bounds__(256) void k_mlp(
    const float* __restrict__ feat, const float* __restrict__ B,
    const float* __restrict__ ba1, const float* __restrict__ Wa2,
    const float* __restrict__ ba2, const float* __restrict__ Wa3,
    const float* __restrict__ ba3, const int* __restrict__ porder,
    const int* __restrict__ sp, float* __restrict__ out0) {
  const int nb = gridDim.x;
  int blk = blockIdx.x;
  if ((nb & 7) == 0) blk = (blockIdx.x & 7) * (nb >> 3) + (blockIdx.x >> 3);
  const int r0 = blk * TA;
  const int tid = threadIdx.x;
  __shared__ int s_a[TA];
  __shared__ __align__(16) float s_fT[NFEAT * TA];   // [i][u]
  __shared__ __align__(16) float s_hT[H1C * TA];     // [j][u]
  __shared__ float s_pre[TA][132];
  __shared__ float s_val[TA][132];
  __shared__ float s_esum[TA];
  if (tid < TA) s_a[tid] = porder[r0 + tid];
  __syncthreads();
  if (s_a[0] < 0) return;
  const int s = sp[s_a[0]];
  for (int idx = tid; idx < TA * 54; idx += 256) {
    int u = idx / 54, q = idx - u * 54;
    int a = s_a[u];
    float4 v = make_float4(0, 0, 0, 0);
    if (a >= 0) v = *(const float4*)(feat + (size_t)a * NFEAT + q * 4);
    s_fT[(q * 4 + 0) * TA + u] = v.x;
    s_fT[(q * 4 + 1) * TA + u] = v.y;
    s_fT[(q * 4 + 2) * TA + u] = v.z;
    s_fT[(q * 4 + 3) * TA + u] = v.w;
  }
  __syncthreads();
  // ---- layer1: thread o computes h1[o] for both atoms, into LDS ----
  {
    const int o = tid;
    float2 A0 = make_float2(0.0f, 0.0f);
    const float* Bp = B + ((size_t)s * NFEAT) * H1C + o;
    #pragma unroll 8
    for (int i = 0; i < NFEAT; ++i) {
      float bv = Bp[(size_t)i * H1C];
      float2 f0 = *(const float2*)&s_fT[i * TA];
      A0.x += bv * f0.x;
      A0.y += bv * f0.y;
    }
    const float b1v = ba1[o];
    s_hT[o * TA + 0] = silu(A0.x + b1v);
    s_hT[o * TA + 1] = silu(A0.y + b1v);
  }
  __syncthreads();
  // ---- layer2: o = tid&127, half = tid>>7 ----
  {
    const int o = tid & 127;
    const int half = tid >> 7;
    float2 A0 = make_float2(0.0f, 0.0f);
    const int j0 = half * 128;
    #pragma unroll 8
    for (int j = j0; j < j0 + 128; ++j) {
      float wv = Wa2[j * H2C + o];
      float2 h0 = *(const float2*)&s_hT[j * TA];
      A0.x += wv * h0.x;
      A0.y += wv * h0.y;
    }
    float pa[TA] = {A0.x, A0.y};
    if (half == 0) {
      #pragma unroll
      for (int u = 0; u < TA; ++u) s_pre[u][o] = pa[u];
    }
    __syncthreads();
    if (half == 1) {
      float b = ba2[o], w3 = Wa3[o];
      #pragma unroll
      for (int u = 0; u < TA; ++u)
        s_val[u][o] = silu(s_pre[u][o] + pa[u] + b) * w3;
    }
  }
  __syncthreads();
  // ---- per-atom energy, tile partial, single atomicAdd ----
  if (tid < TA) {
    int a = s_a[tid];
    float ssum = 0.0f;
    if (a >= 0) {
      for (int k = 0; k < H2C; ++k) ssum += s_val[tid][k];
      ssum += ba3[0];
    }
    s_esum[tid] = ssum;
  }
  __syncthreads();
  if (tid == 0) {
    float tot = 0.0f;
    #pragma unroll
    for (int u = 0; u < TA; ++u) tot += s_esum[u];
    atomicAdd(out0, tot);
  }
}

extern "C" void kernel_launch(void* const* d_in, const int* in_sizes, int n_in,
                              void* d_out, int out_size, void* d_ws, size_t ws_size,
                              hipStream_t stream) {
  const float* rij = (const float*)d_in[0];
  const float* Wr1 = (const float*)d_in[1];
  const float* br1 = (const float*)d_in[2];
  const float* Wr2 = (const float*)d_in[3];
  const float* br2 = (const float*)d_in[4];
  const float* Ws1 = (const float*)d_in[5];
  const float* bs1 = (const float*)d_in[6];
  const float* Ws2 = (const float*)d_in[7];
  const float* bs2 = (const float*)d_in[8];
  const float* Wa1 = (const float*)d_in[9];
  const float* ba1 = (const float*)d_in[10];
  const float* Wa2 = (const float*)d_in[11];
  const float* ba2 = (const float*)d_in[12];
  const float* Wa3 = (const float*)d_in[13];
  const float* ba3 = (const float*)d_in[14];
  const int* fai = (const int*)d_in[15];
  const int* spc = (const int*)d_in[16];

  const int E = in_sizes[0] / 3;
  const int nat = in_sizes[16];

  float* ws = (float*)d_ws;
  size_t off = 0;
  float* radial = ws + off; off += (size_t)E * 120;     // edge-major float4 [E][30]
  float* feat = ws + off;  off += (size_t)nat * NFEAT;
  float* Bm = ws + off;    off += (size_t)NELEMC * NFEAT * H1C;
  int* porder = (int*)(ws + off); off += (size_t)NPT * TA;
  int* bounds = (int*)(ws + off);

  const int nbE = (E + 63) / 64;
  const int nbB = (E + 255) / 256;
  k_front<<<nbE + nbB + 1 + NFEAT * 4, 256, 0, stream>>>(
      rij, Wr1, br1, Wr2, br2, fai, spc, Ws1, bs1, Ws2, bs2, Wa1,
      (float4*)radial, bounds, porder, Bm, (float*)d_out, E, nat, nbE, nbB);
  k_atom<<<nat, 256, 0, stream>>>(rij, (const float4*)radial, bounds, feat, E);
  k_mlp<<<NPT, 256, 0, stream>>>(feat, Bm, ba1, Wa2, ba2, Wa3, ba3,
                                 porder, spc, (float*)d_out);
}

// Round 15
// 195.690 us; speedup vs baseline: 1.0093x; 1.0093x over previous
//
#include <hip/hip_runtime.h>
#include <math.h>

#define KTOT 69
#define NRADC 24
#define NFEAT 216
#define NELEMC 94
#define EMBC 16
#define H1C 256
#define H2C 128
#define CE 16          // edges per chunk in k_atom
#define EPR 20         // padded edge stride for s_radT rows
#define KGN 18         // padded k-groups (72 padded k / 4)
#define GSTR 84        // s_gijT kg-stride
#define GISTR 76       // s_gi rad-stride
#define TA 4           // atoms per species-pure tile (measured optimum)
#define NPT 584        // padded tiles (584*4=2336 >= 2048 + 94*3)

// ---- static lxlylz enumeration (z=1..4 concatenated; real k = 0..68) ----
__device__ __constant__ int c_lx[KTOT] = {
  0,0,0,1,
  0,0,0,1,0,0,0,1,1,2,
  0,0,0,1,0,0,0,1,1,2,0,0,0,0,1,1,1,2,2,3,
  0,0,0,1,0,0,0,1,1,2,0,0,0,0,1,1,1,2,2,3,0,0,0,0,0,1,1,1,1,2,2,2,3,3,4};
__device__ __constant__ int c_ly[KTOT] = {
  0,0,1,0,
  0,0,1,0,0,1,2,0,1,0,
  0,0,1,0,0,1,2,0,1,0,0,1,2,3,0,1,2,0,1,0,
  0,0,1,0,0,1,2,0,1,0,0,1,2,3,0,1,2,0,1,0,0,1,2,3,4,0,1,2,3,0,1,2,0,1,0};
__device__ __constant__ int c_lz[KTOT] = {
  0,1,0,0,
  0,1,0,0,2,1,0,1,0,0,
  0,1,0,0,2,1,0,1,0,0,3,2,1,0,2,1,0,1,0,0,
  0,1,0,0,2,1,0,1,0,0,3,2,1,0,2,1,0,1,0,0,4,3,2,1,0,3,2,1,0,2,1,0,1,0,0};
__device__ __constant__ float c_fn[KTOT] = {
  1,1,1,1,
  1,2,2,2,1,2,1,2,2,1,
  1,3,3,3,3,6,3,6,6,3,1,3,3,1,3,6,3,3,3,1,
  1,4,4,4,6,12,6,12,12,6,4,12,12,4,12,24,12,12,12,4,
  1,4,6,4,1,4,12,12,4,6,12,6,4,4,1};
__device__ __constant__ float c_lam[KTOT] = {
  1,-1,-1,-1,
  1,-1,-1,-1,1,1,1,1,1,1,
  1,-1,-1,-1,1,1,1,1,1,1,-1,-1,-1,-1,-1,-1,-1,-1,-1,-1,
  1,-1,-1,-1,1,1,1,1,1,1,-1,-1,-1,-1,-1,-1,-1,-1,-1,-1,
  1,1,1,1,1,1,1,1,1,1,1,1,1,1,1};
__device__ __constant__ int c_k0[4] = {0,4,14,34};
__device__ __constant__ int c_kn[4] = {4,10,20,35};
__device__ __constant__ float c_zn[4] = {1.0f, 0.5f, 0.25f, 0.125f};
__device__ __constant__ int c_zidg[KGN] = {0, 1,1,1, 2,2,2,2,2, 3,3,3,3,3,3,3,3,3};

__device__ __forceinline__ float silu(float x) { return x / (1.0f + expf(-x)); }
__device__ __forceinline__ float4 silu4(float4 v) {
  v.x = silu(v.x); v.y = silu(v.y); v.z = silu(v.z); v.w = silu(v.w); return v;
}
__device__ __forceinline__ void fma4(float4& a, float s, const float4 w) {
  a.x += s * w.x; a.y += s * w.y; a.z += s * w.z; a.w += s * w.w;
}
__device__ __forceinline__ void fma44(float4& a, const float4 x, const float4 y) {
  a.x += x.x * y.x; a.y += x.y * y.y; a.z += x.z * y.z; a.w += x.w * y.w;
}
__device__ __forceinline__ float hsum4(const float4 v) { return (v.x + v.y) + (v.z + v.w); }
__device__ __forceinline__ float powsel(int l, float p, float p2, float p3, float p4) {
  float v = 1.0f;
  v = l >= 1 ? p : v;
  v = l >= 2 ? p2 : v;
  v = l >= 3 ? p3 : v;
  v = l >= 4 ? p4 : v;
  return v;
}

// ====== k_front: edge radial MLP + bounds + padded sort + B, ONE launch =====
// radial stored COMPONENT-MAJOR: radial4[c4 * E + e] (coalesced stores).
template <int NQ>
__device__ __forceinline__ void edge_l2(
    const float* __restrict__ s_h, const float* __restrict__ Wr2,
    const float* __restrict__ br2, float4* __restrict__ radial4,
    int e, int og, int eg, int E) {
  float4 acc[NQ];
  const float4* b2 = (const float4*)(br2 + og * 32);
  #pragma unroll
  for (int q = 0; q < NQ; ++q) acc[q] = b2[q];
  #pragma unroll 8
  for (int j = 0; j < 64; ++j) {
    float hv = s_h[e * 65 + j];
    const float4* w = (const float4*)(Wr2 + j * 120 + og * 32);
    #pragma unroll
    for (int q = 0; q < NQ; ++q) fma4(acc[q], hv, w[q]);
  }
  if (eg < E) {
    #pragma unroll
    for (int q = 0; q < NQ; ++q)
      radial4[(size_t)(og * 8 + q) * E + eg] = silu4(acc[q]);
  }
}

__global__ __launch_bounds__(256) void k_front(
    const float* __restrict__ rij,
    const float* __restrict__ Wr1, const float* __restrict__ br1,
    const float* __restrict__ Wr2, const float* __restrict__ br2,
    const int* __restrict__ fai, const int* __restrict__ spc,
    const float* __restrict__ Ws1, const float* __restrict__ bs1,
    const float* __restrict__ Ws2, const float* __restrict__ bs2,
    const float* __restrict__ Wa1,
    float4* __restrict__ radial4, int* __restrict__ bounds,
    int* __restrict__ porder, float* __restrict__ B,
    float* __restrict__ out0,
    int E, int nat, int nbE, int nbB) {
  __shared__ __align__(16) float s_mem[64 * 25 + 64 * 65];  // 23 KB union
  const int blk = blockIdx.x;
  const int tid = threadIdx.x;

  if (blk < nbE) {
    // ------------------------- edge branch -------------------------
    float* s_bas = s_mem;              // [64][25]
    float* s_h = s_mem + 64 * 25;      // [64][65]
    const int e = tid & 63;
    const int og = __builtin_amdgcn_readfirstlane(tid >> 6);
    const int eg = blk * 64 + e;
    {
      float x = 0.0f, y = 0.0f, z = 0.0f;
      const bool ev = eg < E;
      if (ev) { x = rij[3 * eg]; y = rij[3 * eg + 1]; z = rij[3 * eg + 2]; }
      float r = sqrtf(x * x + y * y + z * z);
      float fcv = ev ? 0.5f * (cosf(3.14159265358979323846f * fminf(r, 6.0f) *
                                    (1.0f / 6.0f)) + 1.0f)
                     : 0.0f;
      #pragma unroll
      for (int t = 0; t < 6; ++t) {
        int m = og * 6 + t;
        float d = r - (6.0f / 23.0f) * (float)m;
        s_bas[e * 25 + m] = expf(-8.0f * d * d) * fcv;
      }
    }
    __syncthreads();
    {
      const float4* b1 = (const float4*)(br1 + og * 16);
      float4 acc[4] = {b1[0], b1[1], b1[2], b1[3]};
      #pragma unroll 8
      for (int m = 0; m < NRADC; ++m) {
        float b = s_bas[e * 25 + m];
        const float4* w = (const float4*)(Wr1 + m * 64 + og * 16);
        #pragma unroll
        for (int q = 0; q < 4; ++q) fma4(acc[q], b, w[q]);
      }
      #pragma unroll
      for (int q = 0; q < 4; ++q) {
        float4 v = silu4(acc[q]);
        float* dst = &s_h[e * 65 + og * 16 + 4 * q];
        dst[0] = v.x; dst[1] = v.y; dst[2] = v.z; dst[3] = v.w;
      }
    }
    __syncthreads();
    if (og < 3) edge_l2<8>(s_h, Wr2, br2, radial4, e, og, eg, E);
    else        edge_l2<6>(s_h, Wr2, br2, radial4, e, og, eg, E);
  } else if (blk < nbE + nbB) {
    // ------------------------- bounds branch -----------------------
    int e = (blk - nbE) * 256 + tid;
    if (e < E) {
      int f = fai[e];
      int fp = (e == 0) ? -1 : fai[e - 1];
      for (int a = fp + 1; a <= f; ++a) bounds[a] = e;
      if (e == E - 1)
        for (int a = f + 1; a <= nat; ++a) bounds[a] = E;
    }
  } else if (blk == nbE + nbB) {
    // ------------------------- padded sort + out zero --------------
    int* s_cnt = (int*)s_mem;
    int* s_off = s_cnt + NELEMC;
    if (tid == 0) out0[0] = 0.0f;   // d_out accumulator init (pre-k_mlp)
    for (int i = tid; i < NELEMC; i += 256) s_cnt[i] = 0;
    __syncthreads();
    for (int a = tid; a < nat; a += 256) atomicAdd(&s_cnt[spc[a]], 1);
    __syncthreads();
    if (tid == 0) {
      int run = 0;
      for (int s = 0; s < NELEMC; ++s) {
        s_off[s] = run;
        run += ((s_cnt[s] + TA - 1) / TA) * TA;
      }
    }
    for (int i = tid; i < NPT * TA; i += 256) porder[i] = -1;
    __syncthreads();
    for (int a = tid; a < nat; a += 256) {
      int pos = atomicAdd(&s_off[spc[a]], 1);
      porder[pos] = a;
    }
  } else {
    // ------------------------- B branch ----------------------------
    float* s_hh = s_mem;               // [24][32]
    float* s_emb = s_mem + 24 * 32;    // [24][16]
    const int bi = blk - (nbE + nbB + 1);
    const int i = bi >> 2;
    const int sc0 = (bi & 3) * 24;
    const int scn = min(NELEMC, sc0 + 24) - sc0;
    const int o = tid;
    for (int idx = tid; idx < scn * 32; idx += 256) {
      int s = idx >> 5, c = idx & 31;
      s_hh[idx] = silu(Ws1[(sc0 + s) * 32 + c] + bs1[c]);
    }
    __syncthreads();
    for (int idx = tid; idx < scn * EMBC; idx += 256) {
      int s = idx >> 4, j = idx & 15;
      float acc = bs2[j];
      #pragma unroll
      for (int c = 0; c < 32; ++c) acc += s_hh[s * 32 + c] * Ws2[c * EMBC + j];
      s_emb[idx] = acc;
    }
    __syncthreads();
    float w[EMBC];
    #pragma unroll
    for (int j = 0; j < EMBC; ++j) w[j] = Wa1[(size_t)(i * EMBC + j) * H1C + o];
    for (int s = 0; s < scn; ++s) {
      float acc = 0.0f;
      #pragma unroll
      for (int j = 0; j < EMBC; ++j) acc += s_emb[s * EMBC + j] * w[j];
      B[((size_t)(sc0 + s) * NFEAT + i) * H1C + o] = acc;
    }
  }
}

// ========= k_atom v5: register-tiled + prefetch, component-major radial =====
__global__ __launch_bounds__(256) void k_atom(
    const float* __restrict__ rij,
    const float4* __restrict__ radial4,
    const int* __restrict__ bounds,
    float* __restrict__ feat, int E) {
  const int a = blockIdx.x;
  const int tid = threadIdx.x;
  __shared__ __align__(16) float s_radT[120 * EPR];
  __shared__ __align__(16) float s_gijT[KGN * GSTR];
  __shared__ __align__(16) float s_gi[NRADC * GISTR];
  __shared__ float s_feat[NFEAT];

  const int start = bounds[a];
  const int end = bounds[a + 1];

  const int e = tid & 15;
  const int sub = tid >> 4;

  const bool is_tile = tid < 216;
  const int eh = (tid < 216) ? (tid / 108) : 0;
  const int tile = (tid < 216) ? (tid % 108) : 0;
  const int rg = tile % 6;
  const int kg = tile / 6;
  const int comp0 = rg * 20 + 1 + c_zidg[kg];
  const bool is_2b = (tid >= 216 && tid < 240);
  const int rad2b = tid - 216;

  const int kstart = sub < 5 ? sub * 5 : 25 + (sub - 5) * 4;
  const int kcnt = sub < 5 ? 5 : 4;
  int t_pk[5], t_addr[5]; float t_fn[5];
  #pragma unroll
  for (int t = 0; t < 5; ++t) {
    int k = (t < kcnt) ? kstart + t : 0;
    t_pk[t] = c_lx[k] | (c_ly[k] << 8) | (c_lz[k] << 16);
    t_fn[t] = c_fn[k];
    int prow = k + (k < 14 ? 0 : 2);
    t_addr[t] = (prow >> 2) * GSTR + (prow & 3) * EPR + e;
  }

  // prefetch mapping for component-major: idx = c4*16 + e_local
  const int pe = tid & 15;        // edge within chunk
  const int pcA = tid >> 4;       // c4 for first load (0..15)
  const int pcB = pcA + 16;       // c4 for second load (16..29), tid<224

  if (tid < 60) {
    int rr = tid / EPR, ec = tid % EPR;
    int fkg = rr < 2 ? 3 : 17;
    int fj = rr < 2 ? 2 + rr : 3;
    s_gijT[fkg * GSTR + fj * EPR + ec] = 0.0f;
  }

  float4 acc[4][4];
  #pragma unroll
  for (int i = 0; i < 4; ++i)
    #pragma unroll
    for (int j = 0; j < 4; ++j) acc[i][j] = make_float4(0, 0, 0, 0);
  float4 acc2b = make_float4(0, 0, 0, 0);

  float4 pfA, pfB;
  float rx, ry, rz;
  auto prefetch = [&](int c0) {
    int ne = end - c0;
    pfA = make_float4(0, 0, 0, 0);
    pfB = make_float4(0, 0, 0, 0);
    const bool ev0 = pe < ne;      // ne<=0 masks everything
    if (ev0) pfA = radial4[(size_t)pcA * E + c0 + pe];
    if (tid < 224 && ev0) pfB = radial4[(size_t)pcB * E + c0 + pe];
    int eg = c0 + e;
    rx = 0.0f; ry = 0.0f; rz = 0.0f;
    if (eg < end) { rx = rij[3 * eg]; ry = rij[3 * eg + 1]; rz = rij[3 * eg + 2]; }
  };
  prefetch(start);

  for (int c0 = start; c0 < end; c0 += CE) {
    __syncthreads();
    {
      int c = pcA * 4;
      s_radT[(c + 0) * EPR + pe] = pfA.x;
      s_radT[(c + 1) * EPR + pe] = pfA.y;
      s_radT[(c + 2) * EPR + pe] = pfA.z;
      s_radT[(c + 3) * EPR + pe] = pfA.w;
      if (tid < 224) {
        int c2 = pcB * 4;
        s_radT[(c2 + 0) * EPR + pe] = pfB.x;
        s_radT[(c2 + 1) * EPR + pe] = pfB.y;
        s_radT[(c2 + 2) * EPR + pe] = pfB.z;
        s_radT[(c2 + 3) * EPR + pe] = pfB.w;
      }
    }
    {
      const bool ev = (c0 + e) < end;
      float r = sqrtf(rx * rx + ry * ry + rz * rz);
      float inv = 1.0f / r;
      float px = rx * inv + 1e-12f, py = ry * inv + 1e-12f, pz = rz * inv + 1e-12f;
      float p2x = px * px, p3x = p2x * px, p4x = p2x * p2x;
      float p2y = py * py, p3y = p2y * py, p4y = p2y * p2y;
      float p2z = pz * pz, p3z = p2z * pz, p4z = p2z * p2z;
      #pragma unroll
      for (int t = 0; t < 5; ++t) {
        if (t < kcnt) {
          int pk = t_pk[t];
          float g = powsel(pk & 0xff, px, p2x, p3x, p4x) *
                    powsel((pk >> 8) & 0xff, py, p2y, p3y, p4y) *
                    powsel(pk >> 16, pz, p2z, p3z, p4z) * t_fn[t];
          s_gijT[t_addr[t]] = ev ? g : 0.0f;
        }
      }
    }
    __syncthreads();
    prefetch(c0 + CE);
    if (is_tile) {
      #pragma unroll
      for (int s = 0; s < 2; ++s) {
        int e0 = eh * 8 + s * 4;
        float4 gg[4];
        #pragma unroll
        for (int j = 0; j < 4; ++j)
          gg[j] = *(const float4*)&s_gijT[kg * GSTR + j * EPR + e0];
        #pragma unroll
        for (int i = 0; i < 4; ++i) {
          float4 rr = *(const float4*)&s_radT[(comp0 + 5 * i) * EPR + e0];
          #pragma unroll
          for (int j = 0; j < 4; ++j) fma44(acc[i][j], rr, gg[j]);
        }
      }
    }
    if (is_2b) {
      #pragma unroll
      for (int e0 = 0; e0 < 16; e0 += 4) {
        float4 v = *(const float4*)&s_radT[(rad2b * 5) * EPR + e0];
        acc2b.x += v.x; acc2b.y += v.y; acc2b.z += v.z; acc2b.w += v.w;
      }
    }
  }

  float4 hs[4];
  #pragma unroll
  for (int i = 0; i < 4; ++i)
    hs[i] = make_float4(hsum4(acc[i][0]), hsum4(acc[i][1]),
                        hsum4(acc[i][2]), hsum4(acc[i][3]));
  __syncthreads();
  if (is_tile && eh == 0) {
    #pragma unroll
    for (int i = 0; i < 4; ++i)
      *(float4*)&s_gi[(rg * 4 + i) * GISTR + kg * 4] = hs[i];
  }
  if (is_2b) s_feat[rad2b] = hsum4(acc2b);
  __syncthreads();
  if (is_tile && eh == 1) {
    #pragma unroll
    for (int i = 0; i < 4; ++i) {
      float4 v = *(const float4*)&s_gi[(rg * 4 + i) * GISTR + kg * 4];
      v.x += hs[i].x; v.y += hs[i].y; v.z += hs[i].z; v.w += hs[i].w;
      *(float4*)&s_gi[(rg * 4 + i) * GISTR + kg * 4] = v;
    }
  }
  __syncthreads();

  if (tid < 192) {
    int zb = tid / NRADC;
    int rad = tid - zb * NRADC;
    int z = zb >> 1;
    bool neg = zb & 1;
    int k0 = c_k0[z], kn = c_kn[z];
    float s = 0.0f;
    for (int k = k0; k < k0 + kn; ++k) {
      int prow = k + (k < 14 ? 0 : 2);
      float g = s_gi[rad * GISTR + prow];
      float g2 = g * g;
      s += neg ? g2 * c_lam[k] : g2;
    }
    s_feat[NRADC + zb * NRADC + rad] = s * c_zn[z];
  }
  __syncthreads();
  if (tid < NFEAT) feat[(size_t)a * NFEAT + tid] = s_feat[tid];
}

// ====== k_mlp: fused layer1+layer2 per species-pure 4-atom tile + atomic sum =
__global__ __launch_bounds__(256) void k_mlp(
    const float* __restrict__ feat, const float* __restrict__ B,
    const float* __restrict__ ba1, const float* __restrict__ Wa2,
    const float* __restrict__ ba2, const float* __restrict__ Wa3,
    const float* __restrict__ ba3, const int* __restrict__ porder,
    const int* __restrict__ sp, float* __restrict__ out0) {
  const int nb = gridDim.x;
  int blk = blockIdx.x;
  if ((nb & 7) == 0) blk = (blockIdx.x & 7) * (nb >> 3) + (blockIdx.x >> 3);
  const int r0 = blk * TA;
  const int tid = threadIdx.x;
  __shared__ int s_a[TA];
  __shared__ __align__(16) float s_fT[NFEAT * TA];   // [i][u]
  __shared__ __align__(16) float s_hT[H1C * TA];     // [j][u]
  __shared__ float s_pre[TA][132];
  __shared__ float s_val[TA][132];
  __shared__ float s_esum[TA];
  if (tid < TA) s_a[tid] = porder[r0 + tid];
  __syncthreads();
  if (s_a[0] < 0) return;
  const int s = sp[s_a[0]];
  for (int idx = tid; idx < TA * 54; idx += 256) {
    int u = idx / 54, q = idx - u * 54;
    int a = s_a[u];
    float4 v = make_float4(0, 0, 0, 0);
    if (a >= 0) v = *(const float4*)(feat + (size_t)a * NFEAT + q * 4);
    s_fT[(q * 4 + 0) * TA + u] = v.x;
    s_fT[(q * 4 + 1) * TA + u] = v.y;
    s_fT[(q * 4 + 2) * TA + u] = v.z;
    s_fT[(q * 4 + 3) * TA + u] = v.w;
  }
  __syncthreads();
  // ---- layer1: thread o computes h1[o] for all 4 atoms, into LDS ----
  {
    const int o = tid;
    float4 A0 = make_float4(0, 0, 0, 0);
    const float* Bp = B + ((size_t)s * NFEAT) * H1C + o;
    #pragma unroll 8
    for (int i = 0; i < NFEAT; ++i) {
      float bv = Bp[(size_t)i * H1C];
      float4 f0 = *(const float4*)&s_fT[i * TA];
      fma4(A0, bv, f0);
    }
    const float b1v = ba1[o];
    *(float4*)&s_hT[o * TA] = silu4(make_float4(A0.x + b1v, A0.y + b1v,
                                                A0.z + b1v, A0.w + b1v));
  }
  __syncthreads();
  // ---- layer2: o = tid&127, half = tid>>7 ----
  {
    const int o = tid & 127;
    const int half = tid >> 7;
    float4 A0 = make_float4(0, 0, 0, 0);
    const int j0 = half * 128;
    #pragma unroll 8
    for (int j = j0; j < j0 + 128; ++j) {
      float wv = Wa2[j * H2C + o];
      float4 h0 = *(const float4*)&s_hT[j * TA];
      fma4(A0, wv, h0);
    }
    float pa[TA] = {A0.x, A0.y, A0.z, A0.w};
    if (half == 0) {
      #pragma unroll
      for (int u = 0; u < TA; ++u) s_pre[u][o] = pa[u];
    }
    __syncthreads();
    if (half == 1) {
      float b = ba2[o], w3 = Wa3[o];
      #pragma unroll
      for (int u = 0; u < TA; ++u)
        s_val[u][o] = silu(s_pre[u][o] + pa[u] + b) * w3;
    }
  }
  __syncthreads();
  // ---- per-atom energy, tile partial, single atomicAdd ----
  if (tid < TA) {
    int a = s_a[tid];
    float ssum = 0.0f;
    if (a >= 0) {
      for (int k = 0; k < H2C; ++k) ssum += s_val[tid][k];
      ssum += ba3[0];
    }
    s_esum[tid] = ssum;
  }
  __syncthreads();
  if (tid == 0) {
    float tot = 0.0f;
    #pragma unroll
    for (int u = 0; u < TA; ++u) tot += s_esum[u];
    atomicAdd(out0, tot);
  }
}

extern "C" void kernel_launch(void* const* d_in, const int* in_sizes, int n_in,
                              void* d_out, int out_size, void* d_ws, size_t ws_size,
                              hipStream_t stream) {
  const float* rij = (const float*)d_in[0];
  const float* Wr1 = (const float*)d_in[1];
  const float* br1 = (const float*)d_in[2];
  const float* Wr2 = (const float*)d_in[3];
  const float* br2 = (const float*)d_in[4];
  const float* Ws1 = (const float*)d_in[5];
  const float* bs1 = (const float*)d_in[6];
  const float* Ws2 = (const float*)d_in[7];
  const float* bs2 = (const float*)d_in[8];
  const float* Wa1 = (const float*)d_in[9];
  const float* ba1 = (const float*)d_in[10];
  const float* Wa2 = (const float*)d_in[11];
  const float* ba2 = (const float*)d_in[12];
  const float* Wa3 = (const float*)d_in[13];
  const float* ba3 = (const float*)d_in[14];
  const int* fai = (const int*)d_in[15];
  const int* spc = (const int*)d_in[16];

  const int E = in_sizes[0] / 3;
  const int nat = in_sizes[16];

  float* ws = (float*)d_ws;
  size_t off = 0;
  float* radial = ws + off; off += (size_t)E * 120;   // component-major float4 [30][E]
  float* feat = ws + off;  off += (size_t)nat * NFEAT;
  float* Bm = ws + off;    off += (size_t)NELEMC * NFEAT * H1C;
  int* porder = (int*)(ws + off); off += (size_t)NPT * TA;
  int* bounds = (int*)(ws + off);

  const int nbE = (E + 63) / 64;
  const int nbB = (E + 255) / 256;
  k_front<<<nbE + nbB + 1 + NFEAT * 4, 256, 0, stream>>>(
      rij, Wr1, br1, Wr2, br2, fai, spc, Ws1, bs1, Ws2, bs2, Wa1,
      (float4*)radial, bounds, porder, Bm, (float*)d_out, E, nat, nbE, nbB);
  k_atom<<<nat, 256, 0, stream>>>(rij, (const float4*)radial, bounds, feat, E);
  k_mlp<<<NPT, 256, 0, stream>>>(feat, Bm, ba1, Wa2, ba2, Wa3, ba3,
                                 porder, spc, (float*)d_out);
}

// Round 16
// 195.557 us; speedup vs baseline: 1.0100x; 1.0007x over previous
//
#include <hip/hip_runtime.h>
#include <math.h>

#define KTOT 69
#define NRADC 24
#define NFEAT 216
#define NELEMC 94
#define EMBC 16
#define H1C 256
#define H2C 128
#define CE 16          // edges per chunk in k_atom
#define EPR 20         // padded edge stride for s_radT rows
#define KGN 18         // padded k-groups (72 padded k / 4)
#define GSTR 84        // s_gijT kg-stride
#define GISTR 76       // s_gi rad-stride
#define TA 4           // atoms per species-pure tile (measured optimum)
#define NPT 584        // padded tiles (584*4=2336 >= 2048 + 94*3)

// ---- static lxlylz enumeration (z=1..4 concatenated; real k = 0..68) ----
__device__ __constant__ int c_lx[KTOT] = {
  0,0,0,1,
  0,0,0,1,0,0,0,1,1,2,
  0,0,0,1,0,0,0,1,1,2,0,0,0,0,1,1,1,2,2,3,
  0,0,0,1,0,0,0,1,1,2,0,0,0,0,1,1,1,2,2,3,0,0,0,0,0,1,1,1,1,2,2,2,3,3,4};
__device__ __constant__ int c_ly[KTOT] = {
  0,0,1,0,
  0,0,1,0,0,1,2,0,1,0,
  0,0,1,0,0,1,2,0,1,0,0,1,2,3,0,1,2,0,1,0,
  0,0,1,0,0,1,2,0,1,0,0,1,2,3,0,1,2,0,1,0,0,1,2,3,4,0,1,2,3,0,1,2,0,1,0};
__device__ __constant__ int c_lz[KTOT] = {
  0,1,0,0,
  0,1,0,0,2,1,0,1,0,0,
  0,1,0,0,2,1,0,1,0,0,3,2,1,0,2,1,0,1,0,0,
  0,1,0,0,2,1,0,1,0,0,3,2,1,0,2,1,0,1,0,0,4,3,2,1,0,3,2,1,0,2,1,0,1,0,0};
__device__ __constant__ float c_fn[KTOT] = {
  1,1,1,1,
  1,2,2,2,1,2,1,2,2,1,
  1,3,3,3,3,6,3,6,6,3,1,3,3,1,3,6,3,3,3,1,
  1,4,4,4,6,12,6,12,12,6,4,12,12,4,12,24,12,12,12,4,
  1,4,6,4,1,4,12,12,4,6,12,6,4,4,1};
__device__ __constant__ float c_lam[KTOT] = {
  1,-1,-1,-1,
  1,-1,-1,-1,1,1,1,1,1,1,
  1,-1,-1,-1,1,1,1,1,1,1,-1,-1,-1,-1,-1,-1,-1,-1,-1,-1,
  1,-1,-1,-1,1,1,1,1,1,1,-1,-1,-1,-1,-1,-1,-1,-1,-1,-1,
  1,1,1,1,1,1,1,1,1,1,1,1,1,1,1};
__device__ __constant__ int c_k0[4] = {0,4,14,34};
__device__ __constant__ int c_kn[4] = {4,10,20,35};
__device__ __constant__ float c_zn[4] = {1.0f, 0.5f, 0.25f, 0.125f};
__device__ __constant__ int c_zidg[KGN] = {0, 1,1,1, 2,2,2,2,2, 3,3,3,3,3,3,3,3,3};

__device__ __forceinline__ float silu(float x) { return x / (1.0f + expf(-x)); }
__device__ __forceinline__ float4 silu4(float4 v) {
  v.x = silu(v.x); v.y = silu(v.y); v.z = silu(v.z); v.w = silu(v.w); return v;
}
__device__ __forceinline__ void fma4(float4& a, float s, const float4 w) {
  a.x += s * w.x; a.y += s * w.y; a.z += s * w.z; a.w += s * w.w;
}
__device__ __forceinline__ void fma44(float4& a, const float4 x, const float4 y) {
  a.x += x.x * y.x; a.y += x.y * y.y; a.z += x.z * y.z; a.w += x.w * y.w;
}
__device__ __forceinline__ float hsum4(const float4 v) { return (v.x + v.y) + (v.z + v.w); }
__device__ __forceinline__ float powsel(int l, float p, float p2, float p3, float p4) {
  float v = 1.0f;
  v = l >= 1 ? p : v;
  v = l >= 2 ? p2 : v;
  v = l >= 3 ? p3 : v;
  v = l >= 4 ? p4 : v;
  return v;
}

// ====== k_front: edge radial MLP + bounds + padded sort + B, ONE launch =====
// radial stored COMPONENT-MAJOR with PADDED stride: radial4[c4 * Epad + e]
// (coalesced stores; +256 elem pad de-aliases the 1 MiB power-of-2 row stride)
template <int NQ>
__device__ __forceinline__ void edge_l2(
    const float* __restrict__ s_h, const float* __restrict__ Wr2,
    const float* __restrict__ br2, float4* __restrict__ radial4,
    int e, int og, int eg, int E, int Epad) {
  float4 acc[NQ];
  const float4* b2 = (const float4*)(br2 + og * 32);
  #pragma unroll
  for (int q = 0; q < NQ; ++q) acc[q] = b2[q];
  #pragma unroll 8
  for (int j = 0; j < 64; ++j) {
    float hv = s_h[e * 65 + j];
    const float4* w = (const float4*)(Wr2 + j * 120 + og * 32);
    #pragma unroll
    for (int q = 0; q < NQ; ++q) fma4(acc[q], hv, w[q]);
  }
  if (eg < E) {
    #pragma unroll
    for (int q = 0; q < NQ; ++q)
      radial4[(size_t)(og * 8 + q) * Epad + eg] = silu4(acc[q]);
  }
}

__global__ __launch_bounds__(256) void k_front(
    const float* __restrict__ rij,
    const float* __restrict__ Wr1, const float* __restrict__ br1,
    const float* __restrict__ Wr2, const float* __restrict__ br2,
    const int* __restrict__ fai, const int* __restrict__ spc,
    const float* __restrict__ Ws1, const float* __restrict__ bs1,
    const float* __restrict__ Ws2, const float* __restrict__ bs2,
    const float* __restrict__ Wa1,
    float4* __restrict__ radial4, int* __restrict__ bounds,
    int* __restrict__ porder, float* __restrict__ B,
    float* __restrict__ out0,
    int E, int Epad, int nat, int nbE, int nbB) {
  __shared__ __align__(16) float s_mem[64 * 25 + 64 * 65];  // 23 KB union
  const int blk = blockIdx.x;
  const int tid = threadIdx.x;

  if (blk < nbE) {
    // ------------------------- edge branch -------------------------
    float* s_bas = s_mem;              // [64][25]
    float* s_h = s_mem + 64 * 25;      // [64][65]
    const int e = tid & 63;
    const int og = __builtin_amdgcn_readfirstlane(tid >> 6);
    const int eg = blk * 64 + e;
    {
      float x = 0.0f, y = 0.0f, z = 0.0f;
      const bool ev = eg < E;
      if (ev) { x = rij[3 * eg]; y = rij[3 * eg + 1]; z = rij[3 * eg + 2]; }
      float r = sqrtf(x * x + y * y + z * z);
      float fcv = ev ? 0.5f * (cosf(3.14159265358979323846f * fminf(r, 6.0f) *
                                    (1.0f / 6.0f)) + 1.0f)
                     : 0.0f;
      #pragma unroll
      for (int t = 0; t < 6; ++t) {
        int m = og * 6 + t;
        float d = r - (6.0f / 23.0f) * (float)m;
        s_bas[e * 25 + m] = expf(-8.0f * d * d) * fcv;
      }
    }
    __syncthreads();
    {
      const float4* b1 = (const float4*)(br1 + og * 16);
      float4 acc[4] = {b1[0], b1[1], b1[2], b1[3]};
      #pragma unroll 8
      for (int m = 0; m < NRADC; ++m) {
        float b = s_bas[e * 25 + m];
        const float4* w = (const float4*)(Wr1 + m * 64 + og * 16);
        #pragma unroll
        for (int q = 0; q < 4; ++q) fma4(acc[q], b, w[q]);
      }
      #pragma unroll
      for (int q = 0; q < 4; ++q) {
        float4 v = silu4(acc[q]);
        float* dst = &s_h[e * 65 + og * 16 + 4 * q];
        dst[0] = v.x; dst[1] = v.y; dst[2] = v.z; dst[3] = v.w;
      }
    }
    __syncthreads();
    if (og < 3) edge_l2<8>(s_h, Wr2, br2, radial4, e, og, eg, E, Epad);
    else        edge_l2<6>(s_h, Wr2, br2, radial4, e, og, eg, E, Epad);
  } else if (blk < nbE + nbB) {
    // ------------------------- bounds branch -----------------------
    int e = (blk - nbE) * 256 + tid;
    if (e < E) {
      int f = fai[e];
      int fp = (e == 0) ? -1 : fai[e - 1];
      for (int a = fp + 1; a <= f; ++a) bounds[a] = e;
      if (e == E - 1)
        for (int a = f + 1; a <= nat; ++a) bounds[a] = E;
    }
  } else if (blk == nbE + nbB) {
    // ------------------------- padded sort + out zero --------------
    int* s_cnt = (int*)s_mem;
    int* s_off = s_cnt + NELEMC;
    if (tid == 0) out0[0] = 0.0f;   // d_out accumulator init (pre-k_mlp)
    for (int i = tid; i < NELEMC; i += 256) s_cnt[i] = 0;
    __syncthreads();
    for (int a = tid; a < nat; a += 256) atomicAdd(&s_cnt[spc[a]], 1);
    __syncthreads();
    if (tid == 0) {
      int run = 0;
      for (int s = 0; s < NELEMC; ++s) {
        s_off[s] = run;
        run += ((s_cnt[s] + TA - 1) / TA) * TA;
      }
    }
    for (int i = tid; i < NPT * TA; i += 256) porder[i] = -1;
    __syncthreads();
    for (int a = tid; a < nat; a += 256) {
      int pos = atomicAdd(&s_off[spc[a]], 1);
      porder[pos] = a;
    }
  } else {
    // ------------------------- B branch ----------------------------
    float* s_hh = s_mem;               // [24][32]
    float* s_emb = s_mem + 24 * 32;    // [24][16]
    const int bi = blk - (nbE + nbB + 1);
    const int i = bi >> 2;
    const int sc0 = (bi & 3) * 24;
    const int scn = min(NELEMC, sc0 + 24) - sc0;
    const int o = tid;
    for (int idx = tid; idx < scn * 32; idx += 256) {
      int s = idx >> 5, c = idx & 31;
      s_hh[idx] = silu(Ws1[(sc0 + s) * 32 + c] + bs1[c]);
    }
    __syncthreads();
    for (int idx = tid; idx < scn * EMBC; idx += 256) {
      int s = idx >> 4, j = idx & 15;
      float acc = bs2[j];
      #pragma unroll
      for (int c = 0; c < 32; ++c) acc += s_hh[s * 32 + c] * Ws2[c * EMBC + j];
      s_emb[idx] = acc;
    }
    __syncthreads();
    float w[EMBC];
    #pragma unroll
    for (int j = 0; j < EMBC; ++j) w[j] = Wa1[(size_t)(i * EMBC + j) * H1C + o];
    for (int s = 0; s < scn; ++s) {
      float acc = 0.0f;
      #pragma unroll
      for (int j = 0; j < EMBC; ++j) acc += s_emb[s * EMBC + j] * w[j];
      B[((size_t)(sc0 + s) * NFEAT + i) * H1C + o] = acc;
    }
  }
}

// ========= k_atom v6: register-tiled + prefetch, padded component-major =====
__global__ __launch_bounds__(256) void k_atom(
    const float* __restrict__ rij,
    const float4* __restrict__ radial4,
    const int* __restrict__ bounds,
    float* __restrict__ feat, int E, int Epad) {
  const int a = blockIdx.x;
  const int tid = threadIdx.x;
  __shared__ __align__(16) float s_radT[120 * EPR];
  __shared__ __align__(16) float s_gijT[KGN * GSTR];
  __shared__ __align__(16) float s_gi[NRADC * GISTR];
  __shared__ float s_feat[NFEAT];

  const int start = bounds[a];
  const int end = bounds[a + 1];

  const int e = tid & 15;
  const int sub = tid >> 4;

  const bool is_tile = tid < 216;
  const int eh = (tid < 216) ? (tid / 108) : 0;
  const int tile = (tid < 216) ? (tid % 108) : 0;
  const int rg = tile % 6;
  const int kg = tile / 6;
  const int comp0 = rg * 20 + 1 + c_zidg[kg];
  const bool is_2b = (tid >= 216 && tid < 240);
  const int rad2b = tid - 216;

  const int kstart = sub < 5 ? sub * 5 : 25 + (sub - 5) * 4;
  const int kcnt = sub < 5 ? 5 : 4;
  int t_pk[5], t_addr[5]; float t_fn[5];
  #pragma unroll
  for (int t = 0; t < 5; ++t) {
    int k = (t < kcnt) ? kstart + t : 0;
    t_pk[t] = c_lx[k] | (c_ly[k] << 8) | (c_lz[k] << 16);
    t_fn[t] = c_fn[k];
    int prow = k + (k < 14 ? 0 : 2);
    t_addr[t] = (prow >> 2) * GSTR + (prow & 3) * EPR + e;
  }

  // prefetch mapping for component-major: idx = c4*16 + e_local
  const int pe = tid & 15;        // edge within chunk
  const int pcA = tid >> 4;       // c4 for first load (0..15)
  const int pcB = pcA + 16;       // c4 for second load (16..29), tid<224

  if (tid < 60) {
    int rr = tid / EPR, ec = tid % EPR;
    int fkg = rr < 2 ? 3 : 17;
    int fj = rr < 2 ? 2 + rr : 3;
    s_gijT[fkg * GSTR + fj * EPR + ec] = 0.0f;
  }

  float4 acc[4][4];
  #pragma unroll
  for (int i = 0; i < 4; ++i)
    #pragma unroll
    for (int j = 0; j < 4; ++j) acc[i][j] = make_float4(0, 0, 0, 0);
  float4 acc2b = make_float4(0, 0, 0, 0);

  float4 pfA, pfB;
  float rx, ry, rz;
  auto prefetch = [&](int c0) {
    int ne = end - c0;
    pfA = make_float4(0, 0, 0, 0);
    pfB = make_float4(0, 0, 0, 0);
    const bool ev0 = pe < ne;      // ne<=0 masks everything
    if (ev0) pfA = radial4[(size_t)pcA * Epad + c0 + pe];
    if (tid < 224 && ev0) pfB = radial4[(size_t)pcB * Epad + c0 + pe];
    int eg = c0 + e;
    rx = 0.0f; ry = 0.0f; rz = 0.0f;
    if (eg < end) { rx = rij[3 * eg]; ry = rij[3 * eg + 1]; rz = rij[3 * eg + 2]; }
  };
  prefetch(start);

  for (int c0 = start; c0 < end; c0 += CE) {
    __syncthreads();
    {
      int c = pcA * 4;
      s_radT[(c + 0) * EPR + pe] = pfA.x;
      s_radT[(c + 1) * EPR + pe] = pfA.y;
      s_radT[(c + 2) * EPR + pe] = pfA.z;
      s_radT[(c + 3) * EPR + pe] = pfA.w;
      if (tid < 224) {
        int c2 = pcB * 4;
        s_radT[(c2 + 0) * EPR + pe] = pfB.x;
        s_radT[(c2 + 1) * EPR + pe] = pfB.y;
        s_radT[(c2 + 2) * EPR + pe] = pfB.z;
        s_radT[(c2 + 3) * EPR + pe] = pfB.w;
      }
    }
    {
      const bool ev = (c0 + e) < end;
      float r = sqrtf(rx * rx + ry * ry + rz * rz);
      float inv = 1.0f / r;
      float px = rx * inv + 1e-12f, py = ry * inv + 1e-12f, pz = rz * inv + 1e-12f;
      float p2x = px * px, p3x = p2x * px, p4x = p2x * p2x;
      float p2y = py * py, p3y = p2y * py, p4y = p2y * p2y;
      float p2z = pz * pz, p3z = p2z * pz, p4z = p2z * p2z;
      #pragma unroll
      for (int t = 0; t < 5; ++t) {
        if (t < kcnt) {
          int pk = t_pk[t];
          float g = powsel(pk & 0xff, px, p2x, p3x, p4x) *
                    powsel((pk >> 8) & 0xff, py, p2y, p3y, p4y) *
                    powsel(pk >> 16, pz, p2z, p3z, p4z) * t_fn[t];
          s_gijT[t_addr[t]] = ev ? g : 0.0f;
        }
      }
    }
    __syncthreads();
    prefetch(c0 + CE);
    if (is_tile) {
      #pragma unroll
      for (int s = 0; s < 2; ++s) {
        int e0 = eh * 8 + s * 4;
        float4 gg[4];
        #pragma unroll
        for (int j = 0; j < 4; ++j)
          gg[j] = *(const float4*)&s_gijT[kg * GSTR + j * EPR + e0];
        #pragma unroll
        for (int i = 0; i < 4; ++i) {
          float4 rr = *(const float4*)&s_radT[(comp0 + 5 * i) * EPR + e0];
          #pragma unroll
          for (int j = 0; j < 4; ++j) fma44(acc[i][j], rr, gg[j]);
        }
      }
    }
    if (is_2b) {
      #pragma unroll
      for (int e0 = 0; e0 < 16; e0 += 4) {
        float4 v = *(const float4*)&s_radT[(rad2b * 5) * EPR + e0];
        acc2b.x += v.x; acc2b.y += v.y; acc2b.z += v.z; acc2b.w += v.w;
      }
    }
  }

  float4 hs[4];
  #pragma unroll
  for (int i = 0; i < 4; ++i)
    hs[i] = make_float4(hsum4(acc[i][0]), hsum4(acc[i][1]),
                        hsum4(acc[i][2]), hsum4(acc[i][3]));
  __syncthreads();
  if (is_tile && eh == 0) {
    #pragma unroll
    for (int i = 0; i < 4; ++i)
      *(float4*)&s_gi[(rg * 4 + i) * GISTR + kg * 4] = hs[i];
  }
  if (is_2b) s_feat[rad2b] = hsum4(acc2b);
  __syncthreads();
  if (is_tile && eh == 1) {
    #pragma unroll
    for (int i = 0; i < 4; ++i) {
      float4 v = *(const float4*)&s_gi[(rg * 4 + i) * GISTR + kg * 4];
      v.x += hs[i].x; v.y += hs[i].y; v.z += hs[i].z; v.w += hs[i].w;
      *(float4*)&s_gi[(rg * 4 + i) * GISTR + kg * 4] = v;
    }
  }
  __syncthreads();

  if (tid < 192) {
    int zb = tid / NRADC;
    int rad = tid - zb * NRADC;
    int z = zb >> 1;
    bool neg = zb & 1;
    int k0 = c_k0[z], kn = c_kn[z];
    float s = 0.0f;
    for (int k = k0; k < k0 + kn; ++k) {
      int prow = k + (k < 14 ? 0 : 2);
      float g = s_gi[rad * GISTR + prow];
      float g2 = g * g;
      s += neg ? g2 * c_lam[k] : g2;
    }
    s_feat[NRADC + zb * NRADC + rad] = s * c_zn[z];
  }
  __syncthreads();
  if (tid < NFEAT) feat[(size_t)a * NFEAT + tid] = s_feat[tid];
}

// ====== k_mlp: fused layer1+layer2 per species-pure 4-atom tile + atomic sum =
__global__ __launch_bounds__(256) void k_mlp(
    const float* __restrict__ feat, const float* __restrict__ B,
    const float* __restrict__ ba1, const float* __restrict__ Wa2,
    const float* __restrict__ ba2, const float* __restrict__ Wa3,
    const float* __restrict__ ba3, const int* __restrict__ porder,
    const int* __restrict__ sp, float* __restrict__ out0) {
  const int nb = gridDim.x;
  int blk = blockIdx.x;
  if ((nb & 7) == 0) blk = (blockIdx.x & 7) * (nb >> 3) + (blockIdx.x >> 3);
  const int r0 = blk * TA;
  const int tid = threadIdx.x;
  __shared__ int s_a[TA];
  __shared__ __align__(16) float s_fT[NFEAT * TA];   // [i][u]
  __shared__ __align__(16) float s_hT[H1C * TA];     // [j][u]
  __shared__ float s_pre[TA][132];
  __shared__ float s_val[TA][132];
  __shared__ float s_esum[TA];
  if (tid < TA) s_a[tid] = porder[r0 + tid];
  __syncthreads();
  if (s_a[0] < 0) return;
  const int s = sp[s_a[0]];
  for (int idx = tid; idx < TA * 54; idx += 256) {
    int u = idx / 54, q = idx - u * 54;
    int a = s_a[u];
    float4 v = make_float4(0, 0, 0, 0);
    if (a >= 0) v = *(const float4*)(feat + (size_t)a * NFEAT + q * 4);
    s_fT[(q * 4 + 0) * TA + u] = v.x;
    s_fT[(q * 4 + 1) * TA + u] = v.y;
    s_fT[(q * 4 + 2) * TA + u] = v.z;
    s_fT[(q * 4 + 3) * TA + u] = v.w;
  }
  __syncthreads();
  // ---- layer1: thread o computes h1[o] for all 4 atoms, into LDS ----
  {
    const int o = tid;
    float4 A0 = make_float4(0, 0, 0, 0);
    const float* Bp = B + ((size_t)s * NFEAT) * H1C + o;
    #pragma unroll 8
    for (int i = 0; i < NFEAT; ++i) {
      float bv = Bp[(size_t)i * H1C];
      float4 f0 = *(const float4*)&s_fT[i * TA];
      fma4(A0, bv, f0);
    }
    const float b1v = ba1[o];
    *(float4*)&s_hT[o * TA] = silu4(make_float4(A0.x + b1v, A0.y + b1v,
                                                A0.z + b1v, A0.w + b1v));
  }
  __syncthreads();
  // ---- layer2: o = tid&127, half = tid>>7 ----
  {
    const int o = tid & 127;
    const int half = tid >> 7;
    float4 A0 = make_float4(0, 0, 0, 0);
    const int j0 = half * 128;
    #pragma unroll 8
    for (int j = j0; j < j0 + 128; ++j) {
      float wv = Wa2[j * H2C + o];
      float4 h0 = *(const float4*)&s_hT[j * TA];
      fma4(A0, wv, h0);
    }
    float pa[TA] = {A0.x, A0.y, A0.z, A0.w};
    if (half == 0) {
      #pragma unroll
      for (int u = 0; u < TA; ++u) s_pre[u][o] = pa[u];
    }
    __syncthreads();
    if (half == 1) {
      float b = ba2[o], w3 = Wa3[o];
      #pragma unroll
      for (int u = 0; u < TA; ++u)
        s_val[u][o] = silu(s_pre[u][o] + pa[u] + b) * w3;
    }
  }
  __syncthreads();
  // ---- per-atom energy, tile partial, single atomicAdd ----
  if (tid < TA) {
    int a = s_a[tid];
    float ssum = 0.0f;
    if (a >= 0) {
      for (int k = 0; k < H2C; ++k) ssum += s_val[tid][k];
      ssum += ba3[0];
    }
    s_esum[tid] = ssum;
  }
  __syncthreads();
  if (tid == 0) {
    float tot = 0.0f;
    #pragma unroll
    for (int u = 0; u < TA; ++u) tot += s_esum[u];
    atomicAdd(out0, tot);
  }
}

extern "C" void kernel_launch(void* const* d_in, const int* in_sizes, int n_in,
                              void* d_out, int out_size, void* d_ws, size_t ws_size,
                              hipStream_t stream) {
  const float* rij = (const float*)d_in[0];
  const float* Wr1 = (const float*)d_in[1];
  const float* br1 = (const float*)d_in[2];
  const float* Wr2 = (const float*)d_in[3];
  const float* br2 = (const float*)d_in[4];
  const float* Ws1 = (const float*)d_in[5];
  const float* bs1 = (const float*)d_in[6];
  const float* Ws2 = (const float*)d_in[7];
  const float* bs2 = (const float*)d_in[8];
  const float* Wa1 = (const float*)d_in[9];
  const float* ba1 = (const float*)d_in[10];
  const float* Wa2 = (const float*)d_in[11];
  const float* ba2 = (const float*)d_in[12];
  const float* Wa3 = (const float*)d_in[13];
  const float* ba3 = (const float*)d_in[14];
  const int* fai = (const int*)d_in[15];
  const int* spc = (const int*)d_in[16];

  const int E = in_sizes[0] / 3;
  const int Epad = E + 256;   // de-alias 1 MiB row stride (+4 KiB per row)
  const int nat = in_sizes[16];

  float* ws = (float*)d_ws;
  size_t off = 0;
  float* radial = ws + off; off += (size_t)Epad * 120;  // comp-major float4 [30][Epad]
  float* feat = ws + off;  off += (size_t)nat * NFEAT;
  float* Bm = ws + off;    off += (size_t)NELEMC * NFEAT * H1C;
  int* porder = (int*)(ws + off); off += (size_t)NPT * TA;
  int* bounds = (int*)(ws + off);

  const int nbE = (E + 63) / 64;
  const int nbB = (E + 255) / 256;
  k_front<<<nbE + nbB + 1 + NFEAT * 4, 256, 0, stream>>>(
      rij, Wr1, br1, Wr2, br2, fai, spc, Ws1, bs1, Ws2, bs2, Wa1,
      (float4*)radial, bounds, porder, Bm, (float*)d_out, E, Epad, nat, nbE, nbB);
  k_atom<<<nat, 256, 0, stream>>>(rij, (const float4*)radial, bounds, feat, E, Epad);
  k_mlp<<<NPT, 256, 0, stream>>>(feat, Bm, ba1, Wa2, ba2, Wa3, ba3,
                                 porder, spc, (float*)d_out);
}

// Round 17
// 188.233 us; speedup vs baseline: 1.0493x; 1.0389x over previous
//
#include <hip/hip_runtime.h>
#include <math.h>

#define KTOT 69
#define NRADC 24
#define NFEAT 216
#define NELEMC 94
#define EMBC 16
#define H1C 256
#define H2C 128
#define CE 16          // edges per chunk in k_atom
#define EPR 20         // padded edge stride for s_radT rows
#define KGN 18         // padded k-groups (72 padded k / 4)
#define GSTR 84        // s_gijT kg-stride
#define GISTR 76       // s_gi rad-stride
#define TA 4           // atoms per species-pure tile (measured optimum)
#define NPT 584        // padded tiles (584*4=2336 >= 2048 + 94*3)

// ---- static lxlylz enumeration (z=1..4 concatenated; real k = 0..68) ----
__device__ __constant__ int c_lx[KTOT] = {
  0,0,0,1,
  0,0,0,1,0,0,0,1,1,2,
  0,0,0,1,0,0,0,1,1,2,0,0,0,0,1,1,1,2,2,3,
  0,0,0,1,0,0,0,1,1,2,0,0,0,0,1,1,1,2,2,3,0,0,0,0,0,1,1,1,1,2,2,2,3,3,4};
__device__ __constant__ int c_ly[KTOT] = {
  0,0,1,0,
  0,0,1,0,0,1,2,0,1,0,
  0,0,1,0,0,1,2,0,1,0,0,1,2,3,0,1,2,0,1,0,
  0,0,1,0,0,1,2,0,1,0,0,1,2,3,0,1,2,0,1,0,0,1,2,3,4,0,1,2,3,0,1,2,0,1,0};
__device__ __constant__ int c_lz[KTOT] = {
  0,1,0,0,
  0,1,0,0,2,1,0,1,0,0,
  0,1,0,0,2,1,0,1,0,0,3,2,1,0,2,1,0,1,0,0,
  0,1,0,0,2,1,0,1,0,0,3,2,1,0,2,1,0,1,0,0,4,3,2,1,0,3,2,1,0,2,1,0,1,0,0};
__device__ __constant__ float c_fn[KTOT] = {
  1,1,1,1,
  1,2,2,2,1,2,1,2,2,1,
  1,3,3,3,3,6,3,6,6,3,1,3,3,1,3,6,3,3,3,1,
  1,4,4,4,6,12,6,12,12,6,4,12,12,4,12,24,12,12,12,4,
  1,4,6,4,1,4,12,12,4,6,12,6,4,4,1};
__device__ __constant__ float c_lam[KTOT] = {
  1,-1,-1,-1,
  1,-1,-1,-1,1,1,1,1,1,1,
  1,-1,-1,-1,1,1,1,1,1,1,-1,-1,-1,-1,-1,-1,-1,-1,-1,-1,
  1,-1,-1,-1,1,1,1,1,1,1,-1,-1,-1,-1,-1,-1,-1,-1,-1,-1,
  1,1,1,1,1,1,1,1,1,1,1,1,1,1,1};
__device__ __constant__ int c_k0[4] = {0,4,14,34};
__device__ __constant__ int c_kn[4] = {4,10,20,35};
__device__ __constant__ float c_zn[4] = {1.0f, 0.5f, 0.25f, 0.125f};
__device__ __constant__ int c_zidg[KGN] = {0, 1,1,1, 2,2,2,2,2, 3,3,3,3,3,3,3,3,3};

__device__ __forceinline__ float silu(float x) { return x / (1.0f + expf(-x)); }
__device__ __forceinline__ float4 silu4(float4 v) {
  v.x = silu(v.x); v.y = silu(v.y); v.z = silu(v.z); v.w = silu(v.w); return v;
}
__device__ __forceinline__ void fma4(float4& a, float s, const float4 w) {
  a.x += s * w.x; a.y += s * w.y; a.z += s * w.z; a.w += s * w.w;
}
__device__ __forceinline__ void fma44(float4& a, const float4 x, const float4 y) {
  a.x += x.x * y.x; a.y += x.y * y.y; a.z += x.z * y.z; a.w += x.w * y.w;
}
__device__ __forceinline__ float hsum4(const float4 v) { return (v.x + v.y) + (v.z + v.w); }
__device__ __forceinline__ float powsel(int l, float p, float p2, float p3, float p4) {
  float v = 1.0f;
  v = l >= 1 ? p : v;
  v = l >= 2 ? p2 : v;
  v = l >= 3 ? p3 : v;
  v = l >= 4 ? p4 : v;
  return v;
}

// ====== k_front: edge radial MLP + bounds + padded sort + B, ONE launch =====
template <int NQ>
__device__ __forceinline__ void edge_l2(
    const float* __restrict__ s_h, const float* __restrict__ Wr2,
    const float* __restrict__ br2, float4* __restrict__ radial4,
    int e, int og, int eg, int E) {
  float4 acc[NQ];
  const float4* b2 = (const float4*)(br2 + og * 32);
  #pragma unroll
  for (int q = 0; q < NQ; ++q) acc[q] = b2[q];
  #pragma unroll 8
  for (int j = 0; j < 64; ++j) {
    float hv = s_h[e * 65 + j];
    const float4* w = (const float4*)(Wr2 + j * 120 + og * 32);
    #pragma unroll
    for (int q = 0; q < NQ; ++q) fma4(acc[q], hv, w[q]);
  }
  if (eg < E) {
    #pragma unroll
    for (int q = 0; q < NQ; ++q)
      radial4[(size_t)eg * 30 + og * 8 + q] = silu4(acc[q]);
  }
}

__global__ __launch_bounds__(256) void k_front(
    const float* __restrict__ rij,
    const float* __restrict__ Wr1, const float* __restrict__ br1,
    const float* __restrict__ Wr2, const float* __restrict__ br2,
    const int* __restrict__ fai, const int* __restrict__ spc,
    const float* __restrict__ Ws1, const float* __restrict__ bs1,
    const float* __restrict__ Ws2, const float* __restrict__ bs2,
    const float* __restrict__ Wa1,
    float4* __restrict__ radial4, int* __restrict__ bounds,
    int* __restrict__ porder, float* __restrict__ B,
    float* __restrict__ out0,
    int E, int nat, int nbE, int nbB) {
  __shared__ __align__(16) float s_mem[64 * 25 + 64 * 65];  // 23 KB union
  const int blk = blockIdx.x;
  const int tid = threadIdx.x;

  if (blk < nbE) {
    // ------------------------- edge branch -------------------------
    float* s_bas = s_mem;              // [64][25]
    float* s_h = s_mem + 64 * 25;      // [64][65]
    const int e = tid & 63;
    const int og = __builtin_amdgcn_readfirstlane(tid >> 6);
    const int eg = blk * 64 + e;
    {
      float x = 0.0f, y = 0.0f, z = 0.0f;
      const bool ev = eg < E;
      if (ev) { x = rij[3 * eg]; y = rij[3 * eg + 1]; z = rij[3 * eg + 2]; }
      float r = sqrtf(x * x + y * y + z * z);
      float fcv = ev ? 0.5f * (cosf(3.14159265358979323846f * fminf(r, 6.0f) *
                                    (1.0f / 6.0f)) + 1.0f)
                     : 0.0f;
      #pragma unroll
      for (int t = 0; t < 6; ++t) {
        int m = og * 6 + t;
        float d = r - (6.0f / 23.0f) * (float)m;
        s_bas[e * 25 + m] = expf(-8.0f * d * d) * fcv;
      }
    }
    __syncthreads();
    {
      const float4* b1 = (const float4*)(br1 + og * 16);
      float4 acc[4] = {b1[0], b1[1], b1[2], b1[3]};
      #pragma unroll 8
      for (int m = 0; m < NRADC; ++m) {
        float b = s_bas[e * 25 + m];
        const float4* w = (const float4*)(Wr1 + m * 64 + og * 16);
        #pragma unroll
        for (int q = 0; q < 4; ++q) fma4(acc[q], b, w[q]);
      }
      #pragma unroll
      for (int q = 0; q < 4; ++q) {
        float4 v = silu4(acc[q]);
        float* dst = &s_h[e * 65 + og * 16 + 4 * q];
        dst[0] = v.x; dst[1] = v.y; dst[2] = v.z; dst[3] = v.w;
      }
    }
    __syncthreads();
    if (og < 3) edge_l2<8>(s_h, Wr2, br2, radial4, e, og, eg, E);
    else        edge_l2<6>(s_h, Wr2, br2, radial4, e, og, eg, E);
  } else if (blk < nbE + nbB) {
    // ------------------------- bounds branch -----------------------
    int e = (blk - nbE) * 256 + tid;
    if (e < E) {
      int f = fai[e];
      int fp = (e == 0) ? -1 : fai[e - 1];
      for (int a = fp + 1; a <= f; ++a) bounds[a] = e;
      if (e == E - 1)
        for (int a = f + 1; a <= nat; ++a) bounds[a] = E;
    }
  } else if (blk == nbE + nbB) {
    // ------------------------- padded sort + out zero --------------
    int* s_cnt = (int*)s_mem;
    int* s_off = s_cnt + NELEMC;
    if (tid == 0) out0[0] = 0.0f;   // d_out accumulator init (pre-k_mlp)
    for (int i = tid; i < NELEMC; i += 256) s_cnt[i] = 0;
    __syncthreads();
    for (int a = tid; a < nat; a += 256) atomicAdd(&s_cnt[spc[a]], 1);
    __syncthreads();
    if (tid == 0) {
      int run = 0;
      for (int s = 0; s < NELEMC; ++s) {
        s_off[s] = run;
        run += ((s_cnt[s] + TA - 1) / TA) * TA;
      }
    }
    for (int i = tid; i < NPT * TA; i += 256) porder[i] = -1;
    __syncthreads();
    for (int a = tid; a < nat; a += 256) {
      int pos = atomicAdd(&s_off[spc[a]], 1);
      porder[pos] = a;
    }
  } else {
    // ------------------------- B branch ----------------------------
    float* s_hh = s_mem;               // [24][32]
    float* s_emb = s_mem + 24 * 32;    // [24][16]
    const int bi = blk - (nbE + nbB + 1);
    const int i = bi >> 2;
    const int sc0 = (bi & 3) * 24;
    const int scn = min(NELEMC, sc0 + 24) - sc0;
    const int o = tid;
    for (int idx = tid; idx < scn * 32; idx += 256) {
      int s = idx >> 5, c = idx & 31;
      s_hh[idx] = silu(Ws1[(sc0 + s) * 32 + c] + bs1[c]);
    }
    __syncthreads();
    for (int idx = tid; idx < scn * EMBC; idx += 256) {
      int s = idx >> 4, j = idx & 15;
      float acc = bs2[j];
      #pragma unroll
      for (int c = 0; c < 32; ++c) acc += s_hh[s * 32 + c] * Ws2[c * EMBC + j];
      s_emb[idx] = acc;
    }
    __syncthreads();
    float w[EMBC];
    #pragma unroll
    for (int j = 0; j < EMBC; ++j) w[j] = Wa1[(size_t)(i * EMBC + j) * H1C + o];
    for (int s = 0; s < scn; ++s) {
      float acc = 0.0f;
      #pragma unroll
      for (int j = 0; j < EMBC; ++j) acc += s_emb[s * EMBC + j] * w[j];
      B[((size_t)(sc0 + s) * NFEAT + i) * H1C + o] = acc;
    }
  }
}

// ========= k_atom v4: register-tiled + software-pipelined prefetch ==========
__global__ __launch_bounds__(256) void k_atom(
    const float* __restrict__ rij,
    const float4* __restrict__ radial4,
    const int* __restrict__ bounds,
    float* __restrict__ feat, int E) {
  const int a = blockIdx.x;
  const int tid = threadIdx.x;
  __shared__ __align__(16) float s_radT[120 * EPR];
  __shared__ __align__(16) float s_gijT[KGN * GSTR];
  __shared__ __align__(16) float s_gi[NRADC * GISTR];
  __shared__ float s_feat[NFEAT];

  const int start = bounds[a];
  const int end = bounds[a + 1];

  const int e = tid & 15;
  const int sub = tid >> 4;

  const bool is_tile = tid < 216;
  const int eh = (tid < 216) ? (tid / 108) : 0;
  const int tile = (tid < 216) ? (tid % 108) : 0;
  const int rg = tile % 6;
  const int kg = tile / 6;
  const int comp0 = rg * 20 + 1 + c_zidg[kg];
  const bool is_2b = (tid >= 216 && tid < 240);
  const int rad2b = tid - 216;

  const int kstart = sub < 5 ? sub * 5 : 25 + (sub - 5) * 4;
  const int kcnt = sub < 5 ? 5 : 4;
  int t_pk[5], t_addr[5]; float t_fn[5];
  #pragma unroll
  for (int t = 0; t < 5; ++t) {
    int k = (t < kcnt) ? kstart + t : 0;
    t_pk[t] = c_lx[k] | (c_ly[k] << 8) | (c_lz[k] << 16);
    t_fn[t] = c_fn[k];
    int prow = k + (k < 14 ? 0 : 2);
    t_addr[t] = (prow >> 2) * GSTR + (prow & 3) * EPR + e;
  }

  const int pe0 = tid / 30, pc0 = tid - pe0 * 30;
  const int pe1 = (tid + 256) / 30, pc1 = (tid + 256) - pe1 * 30;

  if (tid < 60) {
    int rr = tid / EPR, ec = tid % EPR;
    int fkg = rr < 2 ? 3 : 17;
    int fj = rr < 2 ? 2 + rr : 3;
    s_gijT[fkg * GSTR + fj * EPR + ec] = 0.0f;
  }

  float4 acc[4][4];
  #pragma unroll
  for (int i = 0; i < 4; ++i)
    #pragma unroll
    for (int j = 0; j < 4; ++j) acc[i][j] = make_float4(0, 0, 0, 0);
  float4 acc2b = make_float4(0, 0, 0, 0);

  float4 pfA, pfB;
  float rx, ry, rz;
  auto prefetch = [&](int c0) {
    int lim = (end - c0) * 30;
    pfA = make_float4(0, 0, 0, 0);
    pfB = make_float4(0, 0, 0, 0);
    if (tid < lim) pfA = radial4[(size_t)c0 * 30 + tid];
    if (tid < 224 && tid + 256 < lim) pfB = radial4[(size_t)c0 * 30 + 256 + tid];
    int eg = c0 + e;
    rx = 0.0f; ry = 0.0f; rz = 0.0f;
    if (eg < end) { rx = rij[3 * eg]; ry = rij[3 * eg + 1]; rz = rij[3 * eg + 2]; }
  };
  prefetch(start);

  for (int c0 = start; c0 < end; c0 += CE) {
    __syncthreads();
    {
      int c = pc0 * 4;
      s_radT[(c + 0) * EPR + pe0] = pfA.x;
      s_radT[(c + 1) * EPR + pe0] = pfA.y;
      s_radT[(c + 2) * EPR + pe0] = pfA.z;
      s_radT[(c + 3) * EPR + pe0] = pfA.w;
      if (tid < 224) {
        int c2 = pc1 * 4;
        s_radT[(c2 + 0) * EPR + pe1] = pfB.x;
        s_radT[(c2 + 1) * EPR + pe1] = pfB.y;
        s_radT[(c2 + 2) * EPR + pe1] = pfB.z;
        s_radT[(c2 + 3) * EPR + pe1] = pfB.w;
      }
    }
    {
      const bool ev = (c0 + e) < end;
      float r = sqrtf(rx * rx + ry * ry + rz * rz);
      float inv = 1.0f / r;
      float px = rx * inv + 1e-12f, py = ry * inv + 1e-12f, pz = rz * inv + 1e-12f;
      float p2x = px * px, p3x = p2x * px, p4x = p2x * p2x;
      float p2y = py * py, p3y = p2y * py, p4y = p2y * p2y;
      float p2z = pz * pz, p3z = p2z * pz, p4z = p2z * p2z;
      #pragma unroll
      for (int t = 0; t < 5; ++t) {
        if (t < kcnt) {
          int pk = t_pk[t];
          float g = powsel(pk & 0xff, px, p2x, p3x, p4x) *
                    powsel((pk >> 8) & 0xff, py, p2y, p3y, p4y) *
                    powsel(pk >> 16, pz, p2z, p3z, p4z) * t_fn[t];
          s_gijT[t_addr[t]] = ev ? g : 0.0f;
        }
      }
    }
    __syncthreads();
    prefetch(c0 + CE);
    if (is_tile) {
      #pragma unroll
      for (int s = 0; s < 2; ++s) {
        int e0 = eh * 8 + s * 4;
        float4 gg[4];
        #pragma unroll
        for (int j = 0; j < 4; ++j)
          gg[j] = *(const float4*)&s_gijT[kg * GSTR + j * EPR + e0];
        #pragma unroll
        for (int i = 0; i < 4; ++i) {
          float4 rr = *(const float4*)&s_radT[(comp0 + 5 * i) * EPR + e0];
          #pragma unroll
          for (int j = 0; j < 4; ++j) fma44(acc[i][j], rr, gg[j]);
        }
      }
    }
    if (is_2b) {
      #pragma unroll
      for (int e0 = 0; e0 < 16; e0 += 4) {
        float4 v = *(const float4*)&s_radT[(rad2b * 5) * EPR + e0];
        acc2b.x += v.x; acc2b.y += v.y; acc2b.z += v.z; acc2b.w += v.w;
      }
    }
  }

  float4 hs[4];
  #pragma unroll
  for (int i = 0; i < 4; ++i)
    hs[i] = make_float4(hsum4(acc[i][0]), hsum4(acc[i][1]),
                        hsum4(acc[i][2]), hsum4(acc[i][3]));
  __syncthreads();
  if (is_tile && eh == 0) {
    #pragma unroll
    for (int i = 0; i < 4; ++i)
      *(float4*)&s_gi[(rg * 4 + i) * GISTR + kg * 4] = hs[i];
  }
  if (is_2b) s_feat[rad2b] = hsum4(acc2b);
  __syncthreads();
  if (is_tile && eh == 1) {
    #pragma unroll
    for (int i = 0; i < 4; ++i) {
      float4 v = *(const float4*)&s_gi[(rg * 4 + i) * GISTR + kg * 4];
      v.x += hs[i].x; v.y += hs[i].y; v.z += hs[i].z; v.w += hs[i].w;
      *(float4*)&s_gi[(rg * 4 + i) * GISTR + kg * 4] = v;
    }
  }
  __syncthreads();

  if (tid < 192) {
    int zb = tid / NRADC;
    int rad = tid - zb * NRADC;
    int z = zb >> 1;
    bool neg = zb & 1;
    int k0 = c_k0[z], kn = c_kn[z];
    float s = 0.0f;
    for (int k = k0; k < k0 + kn; ++k) {
      int prow = k + (k < 14 ? 0 : 2);
      float g = s_gi[rad * GISTR + prow];
      float g2 = g * g;
      s += neg ? g2 * c_lam[k] : g2;
    }
    s_feat[NRADC + zb * NRADC + rad] = s * c_zn[z];
  }
  __syncthreads();
  if (tid < NFEAT) feat[(size_t)a * NFEAT + tid] = s_feat[tid];
}

// ====== k_mlp: fused layer1+layer2 per species-pure 4-atom tile + atomic sum =
__global__ __launch_bounds__(256) void k_mlp(
    const float* __restrict__ feat, const float* __restrict__ B,
    const float* __restrict__ ba1, const float* __restrict__ Wa2,
    const float* __restrict__ ba2, const float* __restrict__ Wa3,
    const float* __restrict__ ba3, const int* __restrict__ porder,
    const int* __restrict__ sp, float* __restrict__ out0) {
  const int nb = gridDim.x;
  int blk = blockIdx.x;
  if ((nb & 7) == 0) blk = (blockIdx.x & 7) * (nb >> 3) + (blockIdx.x >> 3);
  const int r0 = blk * TA;
  const int tid = threadIdx.x;
  __shared__ int s_a[TA];
  __shared__ __align__(16) float s_fT[NFEAT * TA];   // [i][u]
  __shared__ __align__(16) float s_hT[H1C * TA];     // [j][u]
  __shared__ float s_pre[TA][132];
  __shared__ float s_val[TA][132];
  __shared__ float s_esum[TA];
  if (tid < TA) s_a[tid] = porder[r0 + tid];
  __syncthreads();
  if (s_a[0] < 0) return;
  const int s = sp[s_a[0]];
  for (int idx = tid; idx < TA * 54; idx += 256) {
    int u = idx / 54, q = idx - u * 54;
    int a = s_a[u];
    float4 v = make_float4(0, 0, 0, 0);
    if (a >= 0) v = *(const float4*)(feat + (size_t)a * NFEAT + q * 4);
    s_fT[(q * 4 + 0) * TA + u] = v.x;
    s_fT[(q * 4 + 1) * TA + u] = v.y;
    s_fT[(q * 4 + 2) * TA + u] = v.z;
    s_fT[(q * 4 + 3) * TA + u] = v.w;
  }
  __syncthreads();
  // ---- layer1: thread o computes h1[o] for all 4 atoms, into LDS ----
  {
    const int o = tid;
    float4 A0 = make_float4(0, 0, 0, 0);
    const float* Bp = B + ((size_t)s * NFEAT) * H1C + o;
    #pragma unroll 8
    for (int i = 0; i < NFEAT; ++i) {
      float bv = Bp[(size_t)i * H1C];
      float4 f0 = *(const float4*)&s_fT[i * TA];
      fma4(A0, bv, f0);
    }
    const float b1v = ba1[o];
    *(float4*)&s_hT[o * TA] = silu4(make_float4(A0.x + b1v, A0.y + b1v,
                                                A0.z + b1v, A0.w + b1v));
  }
  __syncthreads();
  // ---- layer2: o = tid&127, half = tid>>7 ----
  {
    const int o = tid & 127;
    const int half = tid >> 7;
    float4 A0 = make_float4(0, 0, 0, 0);
    const int j0 = half * 128;
    #pragma unroll 8
    for (int j = j0; j < j0 + 128; ++j) {
      float wv = Wa2[j * H2C + o];
      float4 h0 = *(const float4*)&s_hT[j * TA];
      fma4(A0, wv, h0);
    }
    float pa[TA] = {A0.x, A0.y, A0.z, A0.w};
    if (half == 0) {
      #pragma unroll
      for (int u = 0; u < TA; ++u) s_pre[u][o] = pa[u];
    }
    __syncthreads();
    if (half == 1) {
      float b = ba2[o], w3 = Wa3[o];
      #pragma unroll
      for (int u = 0; u < TA; ++u)
        s_val[u][o] = silu(s_pre[u][o] + pa[u] + b) * w3;
    }
  }
  __syncthreads();
  // ---- per-atom energy, tile partial, single atomicAdd ----
  if (tid < TA) {
    int a = s_a[tid];
    float ssum = 0.0f;
    if (a >= 0) {
      for (int k = 0; k < H2C; ++k) ssum += s_val[tid][k];
      ssum += ba3[0];
    }
    s_esum[tid] = ssum;
  }
  __syncthreads();
  if (tid == 0) {
    float tot = 0.0f;
    #pragma unroll
    for (int u = 0; u < TA; ++u) tot += s_esum[u];
    atomicAdd(out0, tot);
  }
}

extern "C" void kernel_launch(void* const* d_in, const int* in_sizes, int n_in,
                              void* d_out, int out_size, void* d_ws, size_t ws_size,
                              hipStream_t stream) {
  const float* rij = (const float*)d_in[0];
  const float* Wr1 = (const float*)d_in[1];
  const float* br1 = (const float*)d_in[2];
  const float* Wr2 = (const float*)d_in[3];
  const float* br2 = (const float*)d_in[4];
  const float* Ws1 = (const float*)d_in[5];
  const float* bs1 = (const float*)d_in[6];
  const float* Ws2 = (const float*)d_in[7];
  const float* bs2 = (const float*)d_in[8];
  const float* Wa1 = (const float*)d_in[9];
  const float* ba1 = (const float*)d_in[10];
  const float* Wa2 = (const float*)d_in[11];
  const float* ba2 = (const float*)d_in[12];
  const float* Wa3 = (const float*)d_in[13];
  const float* ba3 = (const float*)d_in[14];
  const int* fai = (const int*)d_in[15];
  const int* spc = (const int*)d_in[16];

  const int E = in_sizes[0] / 3;
  const int nat = in_sizes[16];

  float* ws = (float*)d_ws;
  size_t off = 0;
  float* radial = ws + off; off += (size_t)E * 120;     // edge-major float4 [E][30]
  float* feat = ws + off;  off += (size_t)nat * NFEAT;
  float* Bm = ws + off;    off += (size_t)NELEMC * NFEAT * H1C;
  int* porder = (int*)(ws + off); off += (size_t)NPT * TA;
  int* bounds = (int*)(ws + off);

  const int nbE = (E + 63) / 64;
  const int nbB = (E + 255) / 256;
  k_front<<<nbE + nbB + 1 + NFEAT * 4, 256, 0, stream>>>(
      rij, Wr1, br1, Wr2, br2, fai, spc, Ws1, bs1, Ws2, bs2, Wa1,
      (float4*)radial, bounds, porder, Bm, (float*)d_out, E, nat, nbE, nbB);
  k_atom<<<nat, 256, 0, stream>>>(rij, (const float4*)radial, bounds, feat, E);
  k_mlp<<<NPT, 256, 0, stream>>>(feat, Bm, ba1, Wa2, ba2, Wa3, ba3,
                                 porder, spc, (float*)d_out);
}